// Round 3
// baseline (460.640 us; speedup 1.0000x reference)
//
#include <hip/hip_runtime.h>

typedef unsigned short u16;
typedef unsigned int u32;
typedef unsigned long long u64;
typedef float f32x4 __attribute__((ext_vector_type(4)));
typedef __bf16 bf16x8 __attribute__((ext_vector_type(8)));
typedef unsigned short u16x8 __attribute__((ext_vector_type(8)));
typedef unsigned short u16x4 __attribute__((ext_vector_type(4)));

#define DEV static __device__ __forceinline__

DEV u16 f2bf(float f) {  // native RNE cast; compiler picks v_cvt_pk when paired
  __bf16 h = (__bf16)f;
  union { __bf16 h; u16 u; } x; x.h = h;
  return x.u;
}

DEV f32x4 mfma16(bf16x8 a, bf16x8 b, f32x4 c) {
  return __builtin_amdgcn_mfma_f32_16x16x32_bf16(a, b, c, 0, 0, 0);
}

// ---- generic BT-GEMM: C[m][n] = (scale*sum_k A[m][k]*B[n][k] + bias[n])*post ----
// A: fp32 or bf16(u16) row-major lda; B: fp32 or bf16 row-major ldb (converted in staging).
// OUT_MODE 0: fp32 row-major (ldc, batch sC)
// OUT_MODE 1: bf16 split-head: row=(b*2048+s), col=(h*64+d) -> [(b*16+h)*2048+s]*64+d
template<int BM, int BN, bool A_F32, bool B_F32, int OUT_MODE, bool HAS_BIAS>
__global__ __launch_bounds__(256) void k_gemm_bt(
    const void* __restrict__ Aptr, const void* __restrict__ Bptr,
    const float* __restrict__ bias, void* __restrict__ Cptr,
    int K, int lda, int ldb, int ldc,
    long sA, long sB, long sC, float scale, float post)
{
  constexpr int WM = BM / 64, WN = BN / 64;
  static_assert(WM * WN == 4, "4 waves");
  constexpr int LDSK = 40;
  __shared__ u16 a_lds[BM * LDSK];
  __shared__ u16 b_lds[BN * LDSK];

  const int t = threadIdx.x;
  const int lane = t & 63, wid = t >> 6;
  const int wm = wid % WM, wn = wid / WM;
  const long a_off = (long)blockIdx.z * sA + (long)blockIdx.x * BM * lda;
  const long b_off = (long)blockIdx.z * sB + (long)blockIdx.y * BN * ldb;
  const float* __restrict__ Af = (const float*)Aptr;
  const u16*  __restrict__ Ab = (const u16*)Aptr;
  const float* __restrict__ Bf = (const float*)Bptr;
  const u16*  __restrict__ Bb = (const u16*)Bptr;

  f32x4 acc[4][4] = {};
  const int fr = lane & 15, kq = (lane >> 4) * 8;

  for (int kt = 0; kt < K; kt += 32) {
#pragma unroll
    for (int i = 0; i < BM / 64; ++i) {
      int idx = t + i * 256;
      int row = idx >> 2, k0 = (idx & 3) * 8;
      long gg = a_off + (long)row * lda + kt + k0;
      u16x8 stg;
      if (A_F32) {
        f32x4 v0 = *(const f32x4*)(Af + gg);
        f32x4 v1 = *(const f32x4*)(Af + gg + 4);
#pragma unroll
        for (int j = 0; j < 4; ++j) { stg[j] = f2bf(v0[j]); stg[4 + j] = f2bf(v1[j]); }
      } else {
        stg = *(const u16x8*)(Ab + gg);
      }
      *(u16x8*)&a_lds[row * LDSK + k0] = stg;
    }
#pragma unroll
    for (int i = 0; i < BN / 64; ++i) {
      int idx = t + i * 256;
      int row = idx >> 2, k0 = (idx & 3) * 8;
      long gg = b_off + (long)row * ldb + kt + k0;
      u16x8 stg;
      if (B_F32) {
        f32x4 v0 = *(const f32x4*)(Bf + gg);
        f32x4 v1 = *(const f32x4*)(Bf + gg + 4);
#pragma unroll
        for (int j = 0; j < 4; ++j) { stg[j] = f2bf(v0[j]); stg[4 + j] = f2bf(v1[j]); }
      } else {
        stg = *(const u16x8*)(Bb + gg);
      }
      *(u16x8*)&b_lds[row * LDSK + k0] = stg;
    }
    __syncthreads();

    bf16x8 af[4], bfr[4];
#pragma unroll
    for (int mi = 0; mi < 4; ++mi)
      af[mi] = *(const bf16x8*)&a_lds[(wm * 64 + mi * 16 + fr) * LDSK + kq];
#pragma unroll
    for (int ni = 0; ni < 4; ++ni)
      bfr[ni] = *(const bf16x8*)&b_lds[(wn * 64 + ni * 16 + fr) * LDSK + kq];
#pragma unroll
    for (int mi = 0; mi < 4; ++mi)
#pragma unroll
      for (int ni = 0; ni < 4; ++ni)
        acc[mi][ni] = mfma16(af[mi], bfr[ni], acc[mi][ni]);
    __syncthreads();
  }

  const int r4 = (lane >> 4) * 4, cc = lane & 15;
#pragma unroll
  for (int mi = 0; mi < 4; ++mi)
#pragma unroll
  for (int ni = 0; ni < 4; ++ni)
#pragma unroll
  for (int rg = 0; rg < 4; ++rg) {
    int row = blockIdx.x * BM + wm * 64 + mi * 16 + r4 + rg;
    int col = blockIdx.y * BN + wn * 64 + ni * 16 + cc;
    float v = acc[mi][ni][rg] * scale;
    if (HAS_BIAS) v += bias[col];
    v *= post;
    if (OUT_MODE == 0) {
      ((float*)Cptr)[(long)blockIdx.z * sC + (long)row * ldc + col] = v;
    } else {
      int b = row >> 11, s = row & 2047, h = col >> 6, d = col & 63;
      ((u16*)Cptr)[(((long)(b * 16 + h) * 2048 + s) << 6) + d] = f2bf(v);
    }
  }
}

// ---- per-head V transpose: (bh, S=2048, 64) -> (bh, 64, S=2048), bf16 ----
__global__ __launch_bounds__(256) void k_transpose_v(const u16* __restrict__ vp,
                                                     u16* __restrict__ vpt) {
  __shared__ u16 tile[64][72];
  const int t = threadIdx.x;
  const long base = (long)blockIdx.y * (2048 * 64);
  const int s0 = blockIdx.x * 64;
#pragma unroll
  for (int i = 0; i < 2; ++i) {
    int idx = t + i * 256;
    int s = idx >> 3, c = (idx & 7) * 8;
    u16x8 v = *(const u16x8*)&vp[base + (long)(s0 + s) * 64 + c];
    *(u16x8*)&tile[s][c] = v;
  }
  __syncthreads();
  const long obase = (long)blockIdx.y * (64 * 2048);
#pragma unroll
  for (int i = 0; i < 2; ++i) {
    int idx = t + i * 256;
    int d = idx >> 3, c = (idx & 7) * 8;
    u16x8 v;
#pragma unroll
    for (int j = 0; j < 8; ++j) v[j] = tile[c + j][d];
    *(u16x8*)&vpt[obase + (long)d * 2048 + s0 + c] = v;
  }
}

// ---- fused attention, swapped-operand layout ----
// grid: x = 16 (128-row q blocks), z = 32 (b*16+h). 4 waves, wave w owns q rows
// [w*32, w*32+32). QK^T computed as mfma(K_frag, Q_frag): C col = q (lane&15),
// C row = k (g*4+rg within 16-k subtile). Softmax is lane-local; cross-lane
// reduce (4 g-groups) deferred to end of pass A. Pass B: recompute scores,
// float4-store normalized P to attn, b64-stage bf16 P in swizzled LDS, PV MFMA.
// Q is pre-scaled by 1/8 in the projection epilogue.
__global__ __launch_bounds__(256, 3) void k_fused_attn(
    const u16* __restrict__ QP, const u16* __restrict__ KP,
    const u16* __restrict__ VPT, float* __restrict__ attn,
    u16* __restrict__ AO)
{
  constexpr int LDK = 72;   // k_lds u16 stride (144 B)
  constexpr int LDV = 136;  // vt_lds u16 stride (272 B)
  __shared__ u16 k_lds[128 * LDK];    // 18432 B
  __shared__ u16 vt_lds[64 * LDV];    // 17408 B
  __shared__ u16 p_lds[4 * 16 * 128]; // 16384 B (per-wave 4 KB, XOR-swizzled)

  const int t = threadIdx.x, lane = t & 63, w = t >> 6;
  const int fr = lane & 15, g = lane >> 4;
  const int zz = blockIdx.z;            // b*16+h
  const int b = zz >> 4, h = zz & 15;
  const int q0 = blockIdx.x * 128;
  const long headQK = (long)zz * (2048 * 64);
  const long headVT = (long)zz * (64 * 2048);

  // Q fragments (B-operand: rows = q = fr), persist across both passes
  bf16x8 aq[2][2];
#pragma unroll
  for (int mi = 0; mi < 2; ++mi)
#pragma unroll
    for (int kk = 0; kk < 2; ++kk)
      aq[mi][kk] = *(const bf16x8*)&QP[headQK +
          (long)(q0 + w * 32 + mi * 16 + fr) * 64 + kk * 32 + g * 8];

  float m[2] = {-1e30f, -1e30f}, l[2] = {0.f, 0.f};

  // ---------------- pass A: row stats (lane-local) ----------------
  for (int kt = 0; kt < 16; ++kt) {
    __syncthreads();
#pragma unroll
    for (int i = 0; i < 4; ++i) {
      int idx = t + i * 256;
      int r = idx >> 3, c = (idx & 7) * 8;
      *(u16x8*)&k_lds[r * LDK + c] =
          *(const u16x8*)&KP[headQK + (long)(kt * 128 + r) * 64 + c];
    }
    __syncthreads();

#pragma unroll
    for (int mi = 0; mi < 2; ++mi) {
      f32x4 c[8];
#pragma unroll
      for (int ni = 0; ni < 8; ++ni) {
        c[ni] = (f32x4){};
#pragma unroll
        for (int kk = 0; kk < 2; ++kk) {
          bf16x8 bk = *(const bf16x8*)&k_lds[(ni * 16 + fr) * LDK + kk * 32 + g * 8];
          c[ni] = mfma16(bk, aq[mi][kk], c[ni]);
        }
      }
      float mx01 = -1e30f, mx23 = -1e30f;
#pragma unroll
      for (int ni = 0; ni < 8; ++ni) {
        mx01 = fmaxf(mx01, fmaxf(c[ni][0], c[ni][1]));
        mx23 = fmaxf(mx23, fmaxf(c[ni][2], c[ni][3]));
      }
      float mn = fmaxf(m[mi], fmaxf(mx01, mx23));
      float s = 0.f;
#pragma unroll
      for (int ni = 0; ni < 8; ++ni)
#pragma unroll
        for (int rg = 0; rg < 4; ++rg) s += __expf(c[ni][rg] - mn);
      l[mi] = l[mi] * __expf(m[mi] - mn) + s;
      m[mi] = mn;
    }
  }

  // cross-lane (g-group) reduce, once
  float invl[2];
#pragma unroll
  for (int mi = 0; mi < 2; ++mi) {
    float mo = m[mi], lo = l[mi];
#pragma unroll
    for (int off = 16; off <= 32; off <<= 1) {
      float m2 = __shfl_xor(mo, off);
      float l2 = __shfl_xor(lo, off);
      float mn = fmaxf(mo, m2);
      lo = lo * __expf(mo - mn) + l2 * __expf(m2 - mn);
      mo = mn;
    }
    m[mi] = mo;
    invl[mi] = 1.0f / lo;
  }

  f32x4 acc[2][4] = {};
  char* pw = (char*)&p_lds[w * 2048];  // 4 KB: 16 q rows x 128 k cols bf16
  const int qrow_base = q0 + w * 32 + fr;

  // ---------------- pass B: attn write + PV ----------------
  for (int kt = 0; kt < 16; ++kt) {
    __syncthreads();
#pragma unroll
    for (int i = 0; i < 4; ++i) {
      int idx = t + i * 256;
      int r = idx >> 3, c = (idx & 7) * 8;
      *(u16x8*)&k_lds[r * LDK + c] =
          *(const u16x8*)&KP[headQK + (long)(kt * 128 + r) * 64 + c];
    }
#pragma unroll
    for (int i = 0; i < 4; ++i) {
      int idx = t + i * 256;
      int d = idx >> 4, c = (idx & 15) * 8;
      *(u16x8*)&vt_lds[d * LDV + c] =
          *(const u16x8*)&VPT[headVT + (long)d * 2048 + kt * 128 + c];
    }
    __syncthreads();

#pragma unroll
    for (int mi = 0; mi < 2; ++mi) {
      const long arow = ((long)zz * 2048 + qrow_base + mi * 16) * 2048 + kt * 128;
#pragma unroll
      for (int ni = 0; ni < 8; ++ni) {
        f32x4 c = (f32x4){};
#pragma unroll
        for (int kk = 0; kk < 2; ++kk) {
          bf16x8 bk = *(const bf16x8*)&k_lds[(ni * 16 + fr) * LDK + kk * 32 + g * 8];
          c = mfma16(bk, aq[mi][kk], c);
        }
        f32x4 p;
#pragma unroll
        for (int rg = 0; rg < 4; ++rg)
          p[rg] = __expf(c[rg] - m[mi]) * invl[mi];
        // vectorized attn store: 4 consecutive k for this lane's q row
        *(f32x4*)&attn[arow + ni * 16 + g * 4] = p;
        // bf16 pack -> swizzled LDS (b64)
        union { u16x4 us; u64 ull; } pk;
#pragma unroll
        for (int rg = 0; rg < 4; ++rg) pk.us[rg] = f2bf(p[rg]);
        int byte = (fr << 8) + ((ni * 16 + g * 4) << 1);
        byte ^= (fr & 7) << 4;
        *(u64*)(pw + byte) = pk.ull;
      }
      // PV: acc += P(16x128) @ VT(64x128)^T
#pragma unroll
      for (int kk = 0; kk < 4; ++kk) {
        int byte = (fr << 8) + ((kk * 32 + g * 8) << 1);
        byte ^= (fr & 7) << 4;
        bf16x8 pa = *(const bf16x8*)(pw + byte);
#pragma unroll
        for (int di = 0; di < 4; ++di) {
          bf16x8 bv = *(const bf16x8*)&vt_lds[(di * 16 + fr) * LDV + kk * 32 + g * 8];
          acc[mi][di] = mfma16(pa, bv, acc[mi][di]);
        }
      }
    }
  }

  // epilogue -> AO (b, s, 1024) bf16; O-frag: row=q=g*4+rg, col=d=di*16+fr
#pragma unroll
  for (int mi = 0; mi < 2; ++mi)
#pragma unroll
  for (int di = 0; di < 4; ++di)
#pragma unroll
  for (int rg = 0; rg < 4; ++rg) {
    int row = q0 + w * 32 + mi * 16 + g * 4 + rg;
    AO[((long)b * 2048 + row) * 1024 + h * 64 + di * 16 + fr] =
        f2bf(acc[mi][di][rg]);
  }
}

extern "C" void kernel_launch(void* const* d_in, const int* in_sizes, int n_in,
                              void* d_out, int out_size, void* d_ws, size_t ws_size,
                              hipStream_t stream) {
  const float* Q  = (const float*)d_in[0];
  const float* Kx = (const float*)d_in[1];
  const float* V  = (const float*)d_in[2];
  const float* Wq = (const float*)d_in[3];
  const float* bq = (const float*)d_in[4];
  const float* Wk = (const float*)d_in[5];
  const float* bk = (const float*)d_in[6];
  const float* Wv = (const float*)d_in[7];
  const float* bv = (const float*)d_in[8];
  const float* Wo = (const float*)d_in[9];
  const float* bo = (const float*)d_in[10];

  float* out  = (float*)d_out;
  float* attn = out + (long)4 * 1024 * 1024;

  char* ws = (char*)d_ws;
  const long MB = 1 << 20;
  u16* QP  = (u16*)(ws + 0 * MB);   // (B,H,S,64) bf16, pre-scaled by 1/8
  u16* KP  = (u16*)(ws + 8 * MB);
  u16* VP  = (u16*)(ws + 16 * MB);
  u16* VPT = (u16*)(ws + 24 * MB);  // (B,H,64,S)
  u16* AO  = (u16*)(ws + 32 * MB);  // (B,S,1024) bf16

  // projections (weights converted f32->bf16 in staging); Q gets post=1/8
  dim3 gP(32, 8, 1);
  k_gemm_bt<128, 128, true, true, 1, true><<<gP, 256, 0, stream>>>(
      Q,  Wq, bq, QP, 1024, 1024, 1024, 0, 0, 0, 0, 1.0f, 0.125f);
  k_gemm_bt<128, 128, true, true, 1, true><<<gP, 256, 0, stream>>>(
      Kx, Wk, bk, KP, 1024, 1024, 1024, 0, 0, 0, 0, 1.0f, 1.0f);
  k_gemm_bt<128, 128, true, true, 1, true><<<gP, 256, 0, stream>>>(
      V,  Wv, bv, VP, 1024, 1024, 1024, 0, 0, 0, 0, 1.0f, 1.0f);

  k_transpose_v<<<dim3(32, 32), 256, 0, stream>>>(VP, VPT);

  k_fused_attn<<<dim3(16, 1, 32), 256, 0, stream>>>(QP, KP, VPT, attn, AO);

  dim3 gO(32, 8, 1);
  k_gemm_bt<128, 128, false, true, 0, true><<<gO, 256, 0, stream>>>(
      AO, Wo, bo, out, 1024, 1024, 1024, 1024, 0, 0, 0, 1.0f, 1.0f);
}

// Round 5
// 360.531 us; speedup vs baseline: 1.2777x; 1.2777x over previous
//
#include <hip/hip_runtime.h>

typedef unsigned short u16;
typedef unsigned int u32;
typedef unsigned long long u64;
typedef float f32x4 __attribute__((ext_vector_type(4)));
typedef __bf16 bf16x8 __attribute__((ext_vector_type(8)));
typedef unsigned short u16x8 __attribute__((ext_vector_type(8)));
typedef unsigned short u16x4 __attribute__((ext_vector_type(4)));

#define DEV static __device__ __forceinline__

DEV u16 f2bf(float f) {  // native RNE cast; compiler pairs into v_cvt_pk_bf16_f32
  __bf16 h = (__bf16)f;
  union { __bf16 h; u16 u; } x; x.h = h;
  return x.u;
}

DEV float fexp2(float x) { return __builtin_amdgcn_exp2f(x); }  // v_exp_f32

DEV f32x4 mfma16(bf16x8 a, bf16x8 b, f32x4 c) {
  return __builtin_amdgcn_mfma_f32_16x16x32_bf16(a, b, c, 0, 0, 0);
}

// ---- bulk fp32 -> bf16 convert: 12 segments of 1M elements ----
// segs 0-3: Q, 4-7: K, 8: Wq, 9: Wk, 10: Wv, 11: Wo
struct PrepArgs { const float* s[12]; u16* d[12]; };

__global__ __launch_bounds__(256) void k_prep(PrepArgs p) {
  int bid = blockIdx.x, seg = bid >> 9;
  const float* __restrict__ s = p.s[seg];
  u16* __restrict__ d = p.d[seg];
  int i = ((bid & 511) << 11) + threadIdx.x * 8;
  f32x4 v0 = *(const f32x4*)(s + i);
  f32x4 v1 = *(const f32x4*)(s + i + 4);
  u16x8 o;
#pragma unroll
  for (int j = 0; j < 4; ++j) { o[j] = f2bf(v0[j]); o[4 + j] = f2bf(v1[j]); }
  *(u16x8*)(d + i) = o;
}

// ---- GEMM, BT layout, BK=64, BN=128, 4 waves (2x2) ----
// MODE 1: merged QKV projections, z = 0/1/2 selects input/weight/bias/output.
//   z<2 : split-head bf16 out, (acc+bias)*post (post only for z==0)
//   z==2: V handled from fp32 input (converted in staging), writes V^T directly
// MODE 0: out-projection, fp32 out + bias. A is bf16 (AO).
struct GArgs {
  const u16* A[3]; const u16* B[3]; const float* bias[3];
  void* C[3]; float post;
};

template<int BM, int MODE>
__global__ __launch_bounds__(256) void k_gemm(GArgs a) {
  constexpr int WTM = BM / 32;          // acc rows per wave
  constexpr int NXY = (4096 / BM) * 8;  // blocks per z
  constexpr int NB = (MODE == 1) ? 3 * NXY : NXY;
  __shared__ u16 a_lds[BM * 72];
  __shared__ u16 b_lds[128 * 72];

  const int t = threadIdx.x, lane = t & 63, wid = t >> 6;
  const int wm = wid & 1, wn = wid >> 1;
  // bijective XCD swizzle: consecutive v share the A panel -> same XCD L2
  const int fid = blockIdx.x;
  const int v = (fid & 7) * (NB >> 3) + (fid >> 3);
  int z, rr;
  if (MODE == 1) { z = v / NXY; rr = v % NXY; } else { z = 0; rr = v; }
  const int xb = rr >> 3, yb = rr & 7;

  const u16* __restrict__ Ab = a.A[z];
  const u16* __restrict__ Bb = a.B[z];
  const float* __restrict__ Vf = (const float*)a.A[2];

  f32x4 acc[WTM][4] = {};
  const int fr = lane & 15, g8 = (lane >> 4) * 8;

  for (int kt = 0; kt < 16; ++kt) {
#pragma unroll
    for (int i = 0; i < BM / 32; ++i) {
      int idx = t + i * 256, row = idx >> 3, c = (idx & 7) * 8;
      u16x8 stg;
      if (MODE == 1 && z == 2) {
        long gg = (long)(xb * BM + row) * 1024 + kt * 64 + c;
        f32x4 u0 = *(const f32x4*)(Vf + gg);
        f32x4 u1 = *(const f32x4*)(Vf + gg + 4);
#pragma unroll
        for (int j = 0; j < 4; ++j) { stg[j] = f2bf(u0[j]); stg[4 + j] = f2bf(u1[j]); }
      } else {
        stg = *(const u16x8*)&Ab[(long)(xb * BM + row) * 1024 + kt * 64 + c];
      }
      *(u16x8*)&a_lds[row * 72 + c] = stg;
    }
#pragma unroll
    for (int i = 0; i < 4; ++i) {
      int idx = t + i * 256, row = idx >> 3, c = (idx & 7) * 8;
      *(u16x8*)&b_lds[row * 72 + c] =
          *(const u16x8*)&Bb[(long)(yb * 128 + row) * 1024 + kt * 64 + c];
    }
    __syncthreads();
#pragma unroll
    for (int kk = 0; kk < 2; ++kk) {
      bf16x8 af[WTM], bq[4];
#pragma unroll
      for (int mi = 0; mi < WTM; ++mi)
        af[mi] = *(const bf16x8*)&a_lds[(wm * (BM / 2) + mi * 16 + fr) * 72 + kk * 32 + g8];
#pragma unroll
      for (int ni = 0; ni < 4; ++ni)
        bq[ni] = *(const bf16x8*)&b_lds[(wn * 64 + ni * 16 + fr) * 72 + kk * 32 + g8];
#pragma unroll
      for (int mi = 0; mi < WTM; ++mi)
#pragma unroll
        for (int ni = 0; ni < 4; ++ni)
          acc[mi][ni] = mfma16(af[mi], bq[ni], acc[mi][ni]);
    }
    __syncthreads();
  }

  const int r4 = (lane >> 4) * 4, cc = lane & 15;
  const float* __restrict__ bias = a.bias[z];
  const float post = (MODE == 1 && z == 0) ? a.post : 1.0f;

#pragma unroll
  for (int mi = 0; mi < WTM; ++mi)
#pragma unroll
  for (int ni = 0; ni < 4; ++ni) {
    const int col = yb * 128 + wn * 64 + ni * 16 + cc;
    const float bv = bias[col];
    const int row0 = xb * BM + wm * (BM / 2) + mi * 16 + r4;
    if (MODE == 0) {
      float* O = (float*)a.C[0];
#pragma unroll
      for (int rg = 0; rg < 4; ++rg)
        O[(long)(row0 + rg) * 1024 + col] = acc[mi][ni][rg] + bv;
    } else if (z < 2) {
      u16* O = (u16*)a.C[z];
#pragma unroll
      for (int rg = 0; rg < 4; ++rg) {
        int row = row0 + rg;
        int b = row >> 11, s = row & 2047, h = col >> 6, d = col & 63;
        O[(((long)(b * 16 + h) * 2048 + s) << 6) + d] =
            f2bf((acc[mi][ni][rg] + bv) * post);
      }
    } else {
      u16* O = (u16*)a.C[2];  // V^T: (b*16+h, 64, 2048)
      int b = row0 >> 11, s = row0 & 2047, h = col >> 6, d = col & 63;
      u16x4 o;
#pragma unroll
      for (int rg = 0; rg < 4; ++rg) o[rg] = f2bf(acc[mi][ni][rg] + bv);
      *(u16x4*)&O[((long)(b * 16 + h) * 64 + d) * 2048 + s] = o;
    }
  }
}

// ---- fused attention, swapped-operand layout, exp2 domain ----
// QP pre-scaled by 0.125*log2(e). grid: x=16 q-blocks, z=32 (b*16+h), 4 waves.
__global__ __launch_bounds__(256, 3) void k_fused_attn(
    const u16* __restrict__ QP, const u16* __restrict__ KP,
    const u16* __restrict__ VPT, float* __restrict__ attn,
    u16* __restrict__ AO)
{
  constexpr int LDK = 72;
  constexpr int LDV = 136;
  __shared__ u16 k_lds[128 * LDK];
  __shared__ u16 vt_lds[64 * LDV];
  __shared__ u16 p_lds[4 * 16 * 128];

  const int t = threadIdx.x, lane = t & 63, w = t >> 6;
  const int fr = lane & 15, g = lane >> 4;
  const int zz = blockIdx.z;
  const int b = zz >> 4, h = zz & 15;
  const int q0 = blockIdx.x * 128;
  const long headQK = (long)zz * (2048 * 64);
  const long headVT = (long)zz * (64 * 2048);

  bf16x8 aq[2][2];
#pragma unroll
  for (int mi = 0; mi < 2; ++mi)
#pragma unroll
    for (int kk = 0; kk < 2; ++kk)
      aq[mi][kk] = *(const bf16x8*)&QP[headQK +
          (long)(q0 + w * 32 + mi * 16 + fr) * 64 + kk * 32 + g * 8];

  float m[2] = {-1e30f, -1e30f}, l[2] = {0.f, 0.f};

  // pass A: row stats (lane-local, exp2 domain)
  for (int kt = 0; kt < 16; ++kt) {
    __syncthreads();
#pragma unroll
    for (int i = 0; i < 4; ++i) {
      int idx = t + i * 256;
      int r = idx >> 3, c = (idx & 7) * 8;
      *(u16x8*)&k_lds[r * LDK + c] =
          *(const u16x8*)&KP[headQK + (long)(kt * 128 + r) * 64 + c];
    }
    __syncthreads();

#pragma unroll
    for (int mi = 0; mi < 2; ++mi) {
      f32x4 c[8];
#pragma unroll
      for (int ni = 0; ni < 8; ++ni) {
        c[ni] = (f32x4){};
#pragma unroll
        for (int kk = 0; kk < 2; ++kk) {
          bf16x8 bk = *(const bf16x8*)&k_lds[(ni * 16 + fr) * LDK + kk * 32 + g * 8];
          c[ni] = mfma16(bk, aq[mi][kk], c[ni]);
        }
      }
      float mx01 = -1e30f, mx23 = -1e30f;
#pragma unroll
      for (int ni = 0; ni < 8; ++ni) {
        mx01 = fmaxf(mx01, fmaxf(c[ni][0], c[ni][1]));
        mx23 = fmaxf(mx23, fmaxf(c[ni][2], c[ni][3]));
      }
      float mn = fmaxf(m[mi], fmaxf(mx01, mx23));
      float s = 0.f;
#pragma unroll
      for (int ni = 0; ni < 8; ++ni)
#pragma unroll
        for (int rg = 0; rg < 4; ++rg) s += fexp2(c[ni][rg] - mn);
      l[mi] = l[mi] * fexp2(m[mi] - mn) + s;
      m[mi] = mn;
    }
  }

  float invl[2];
#pragma unroll
  for (int mi = 0; mi < 2; ++mi) {
    float mo = m[mi], lo = l[mi];
#pragma unroll
    for (int off = 16; off <= 32; off <<= 1) {
      float m2 = __shfl_xor(mo, off);
      float l2 = __shfl_xor(lo, off);
      float mn = fmaxf(mo, m2);
      lo = lo * fexp2(mo - mn) + l2 * fexp2(m2 - mn);
      mo = mn;
    }
    m[mi] = mo;
    invl[mi] = 1.0f / lo;
  }

  f32x4 acc[2][4] = {};
  char* pw = (char*)&p_lds[w * 2048];
  const int qrow_base = q0 + w * 32 + fr;

  // pass B: attn write + PV
  for (int kt = 0; kt < 16; ++kt) {
    __syncthreads();
#pragma unroll
    for (int i = 0; i < 4; ++i) {
      int idx = t + i * 256;
      int r = idx >> 3, c = (idx & 7) * 8;
      *(u16x8*)&k_lds[r * LDK + c] =
          *(const u16x8*)&KP[headQK + (long)(kt * 128 + r) * 64 + c];
    }
#pragma unroll
    for (int i = 0; i < 4; ++i) {
      int idx = t + i * 256;
      int d = idx >> 4, c = (idx & 15) * 8;
      *(u16x8*)&vt_lds[d * LDV + c] =
          *(const u16x8*)&VPT[headVT + (long)d * 2048 + kt * 128 + c];
    }
    __syncthreads();

#pragma unroll
    for (int mi = 0; mi < 2; ++mi) {
      const long arow = ((long)zz * 2048 + qrow_base + mi * 16) * 2048 + kt * 128;
#pragma unroll
      for (int ni = 0; ni < 8; ++ni) {
        f32x4 c = (f32x4){};
#pragma unroll
        for (int kk = 0; kk < 2; ++kk) {
          bf16x8 bk = *(const bf16x8*)&k_lds[(ni * 16 + fr) * LDK + kk * 32 + g * 8];
          c = mfma16(bk, aq[mi][kk], c);
        }
        f32x4 p;
#pragma unroll
        for (int rg = 0; rg < 4; ++rg)
          p[rg] = fexp2(c[rg] - m[mi]) * invl[mi];
        *(f32x4*)&attn[arow + ni * 16 + g * 4] = p;
        union { u16x4 us; u64 ull; } pk;
#pragma unroll
        for (int rg = 0; rg < 4; ++rg) pk.us[rg] = f2bf(p[rg]);
        int byte = (fr << 8) + ((ni * 16 + g * 4) << 1);
        byte ^= (fr & 7) << 4;
        *(u64*)(pw + byte) = pk.ull;
      }
#pragma unroll
      for (int kk = 0; kk < 4; ++kk) {
        int byte = (fr << 8) + ((kk * 32 + g * 8) << 1);
        byte ^= (fr & 7) << 4;
        bf16x8 pa = *(const bf16x8*)(pw + byte);
#pragma unroll
        for (int di = 0; di < 4; ++di) {
          bf16x8 bv = *(const bf16x8*)&vt_lds[(di * 16 + fr) * LDV + kk * 32 + g * 8];
          acc[mi][di] = mfma16(pa, bv, acc[mi][di]);
        }
      }
    }
  }

#pragma unroll
  for (int mi = 0; mi < 2; ++mi)
#pragma unroll
  for (int di = 0; di < 4; ++di)
#pragma unroll
  for (int rg = 0; rg < 4; ++rg) {
    int row = q0 + w * 32 + mi * 16 + g * 4 + rg;
    AO[((long)b * 2048 + row) * 1024 + h * 64 + di * 16 + fr] =
        f2bf(acc[mi][di][rg]);
  }
}

extern "C" void kernel_launch(void* const* d_in, const int* in_sizes, int n_in,
                              void* d_out, int out_size, void* d_ws, size_t ws_size,
                              hipStream_t stream) {
  const float* Q  = (const float*)d_in[0];
  const float* Kx = (const float*)d_in[1];
  const float* V  = (const float*)d_in[2];
  const float* Wq = (const float*)d_in[3];
  const float* bq = (const float*)d_in[4];
  const float* Wk = (const float*)d_in[5];
  const float* bk = (const float*)d_in[6];
  const float* Wv = (const float*)d_in[7];
  const float* bv = (const float*)d_in[8];
  const float* Wo = (const float*)d_in[9];
  const float* bo = (const float*)d_in[10];

  float* out  = (float*)d_out;
  float* attn = out + (long)4 * 1024 * 1024;

  // workspace (48 MB): Qb[0-8] (AO overlays after QKV), Kb[8-16],
  // W bf16 [16-24], QP[24-32], KP[32-40], VPT[40-48]
  char* ws = (char*)d_ws;
  const long MB = 1 << 20;
  u16* Qb  = (u16*)(ws + 0 * MB);
  u16* Kb  = (u16*)(ws + 8 * MB);
  u16* Wqb = (u16*)(ws + 16 * MB);
  u16* Wkb = (u16*)(ws + 18 * MB);
  u16* Wvb = (u16*)(ws + 20 * MB);
  u16* Wob = (u16*)(ws + 22 * MB);
  u16* QP  = (u16*)(ws + 24 * MB);
  u16* KP  = (u16*)(ws + 32 * MB);
  u16* VPT = (u16*)(ws + 40 * MB);
  u16* AO  = (u16*)(ws + 0 * MB);   // overlays Qb (dead after QKV GEMM)

  const int M1 = 1 << 20;
  PrepArgs pa;
  for (int j = 0; j < 4; ++j) { pa.s[j] = Q + (long)j * M1;  pa.d[j] = Qb + (long)j * M1; }
  for (int j = 0; j < 4; ++j) { pa.s[4 + j] = Kx + (long)j * M1; pa.d[4 + j] = Kb + (long)j * M1; }
  pa.s[8] = Wq; pa.d[8] = Wqb;
  pa.s[9] = Wk; pa.d[9] = Wkb;
  pa.s[10] = Wv; pa.d[10] = Wvb;
  pa.s[11] = Wo; pa.d[11] = Wob;
  k_prep<<<6144, 256, 0, stream>>>(pa);

  GArgs gq;
  gq.A[0] = Qb; gq.A[1] = Kb; gq.A[2] = (const u16*)V;
  gq.B[0] = Wqb; gq.B[1] = Wkb; gq.B[2] = Wvb;
  gq.bias[0] = bq; gq.bias[1] = bk; gq.bias[2] = bv;
  gq.C[0] = QP; gq.C[1] = KP; gq.C[2] = VPT;
  gq.post = 0.125f * 1.4426950408889634f;  // fold 1/sqrt(dk) and log2(e) into Q
  k_gemm<128, 1><<<768, 256, 0, stream>>>(gq);

  k_fused_attn<<<dim3(16, 1, 32), 256, 0, stream>>>(QP, KP, VPT, attn, AO);

  GArgs go;
  go.A[0] = AO; go.A[1] = AO; go.A[2] = AO;
  go.B[0] = Wob; go.B[1] = Wob; go.B[2] = Wob;
  go.bias[0] = bo; go.bias[1] = bo; go.bias[2] = bo;
  go.C[0] = out; go.C[1] = out; go.C[2] = out;
  go.post = 1.0f;
  k_gemm<64, 0><<<512, 256, 0, stream>>>(go);
}

// Round 6
// 261.837 us; speedup vs baseline: 1.7593x; 1.3769x over previous
//
#include <hip/hip_runtime.h>

typedef unsigned short u16;
typedef unsigned int u32;
typedef unsigned long long u64;
typedef float f32x4 __attribute__((ext_vector_type(4)));
typedef __bf16 bf16x8 __attribute__((ext_vector_type(8)));
typedef unsigned short u16x8 __attribute__((ext_vector_type(8)));
typedef unsigned short u16x4 __attribute__((ext_vector_type(4)));

#define DEV static __device__ __forceinline__

DEV u16 f2bf(float f) {  // native RNE cast; compiler pairs into v_cvt_pk_bf16_f32
  __bf16 h = (__bf16)f;
  union { __bf16 h; u16 u; } x; x.h = h;
  return x.u;
}

DEV float fexp2(float x) { return __builtin_amdgcn_exp2f(x); }  // v_exp_f32

DEV f32x4 mfma16(bf16x8 a, bf16x8 b, f32x4 c) {
  return __builtin_amdgcn_mfma_f32_16x16x32_bf16(a, b, c, 0, 0, 0);
}

// async global->LDS, 16B per lane. LDS dest is wave-uniform base + lane*16;
// global src is per-lane (pre-swizzled to realize the LDS XOR layout).
DEV void gl_lds16(const u16* g, void* l) {
  __builtin_amdgcn_global_load_lds(
      (const __attribute__((address_space(1))) void*)(const void*)g,
      (__attribute__((address_space(3))) void*)l, 16, 0, 0);
}

// ---- bulk fp32 -> bf16 convert: 16 segments of 1M elements ----
// segs 0-3: Q, 4-7: K, 8-11: V, 12: Wq, 13: Wk, 14: Wv, 15: Wo
struct PrepArgs { const float* s[16]; u16* d[16]; };

__global__ __launch_bounds__(256) void k_prep(PrepArgs p) {
  int bid = blockIdx.x, seg = bid >> 9;
  const float* __restrict__ s = p.s[seg];
  u16* __restrict__ d = p.d[seg];
  int i = ((bid & 511) << 11) + threadIdx.x * 8;
  f32x4 v0 = *(const f32x4*)(s + i);
  f32x4 v1 = *(const f32x4*)(s + i + 4);
  u16x8 o;
#pragma unroll
  for (int j = 0; j < 4; ++j) { o[j] = f2bf(v0[j]); o[4 + j] = f2bf(v1[j]); }
  *(u16x8*)(d + i) = o;
}

// ---- GEMM, BT layout, BK=64, BN=128, 4 waves (2x2), gload_lds staging ----
// LDS layout: linear [row][64] bf16 (128 B/row), XOR-swizzled: 16B-chunk index
// c ^= (row&7); realized by pre-swizzling the global source chunk (rule #21).
// MODE 1: merged QKV projections, z=0/1/2 (Q/K/V). z<2: split-head bf16 out;
//         z==2: writes V^T (b*16+h, 64, 2048) directly.
// MODE 0: out-projection, fp32 out + bias.
struct GArgs {
  const u16* A[3]; const u16* B[3]; const float* bias[3];
  void* C[3]; float post;
};

template<int BM, int MODE>
__global__ __launch_bounds__(256) void k_gemm(GArgs a) {
  constexpr int WTM = BM / 32;          // acc rows per wave
  constexpr int NXY = (4096 / BM) * 8;  // blocks per z
  constexpr int NB = (MODE == 1) ? 3 * NXY : NXY;
  __shared__ u16 a_lds[BM * 64];
  __shared__ u16 b_lds[128 * 64];

  const int t = threadIdx.x, lane = t & 63, wid = t >> 6;
  const int wm = wid & 1, wn = wid >> 1;
  // bijective XCD swizzle (NB % 8 == 0): consecutive v share the A panel
  const int fid = blockIdx.x;
  const int v = (fid & 7) * (NB >> 3) + (fid >> 3);
  int z, rr;
  if (MODE == 1) { z = v / NXY; rr = v % NXY; } else { z = 0; rr = v; }
  const int xb = rr >> 3, yb = rr & 7;

  const u16* __restrict__ Ab = a.A[z];
  const u16* __restrict__ Bb = a.B[z];

  f32x4 acc[WTM][4] = {};
  const int fr = lane & 15, g = (lane >> 4) & 3;
  const int c8s = (lane & 7) ^ ((lane >> 3) & 7);  // source chunk (swizzled)
  const int r8 = lane >> 3;                        // row within 8-row group

  for (int kt = 0; kt < 16; ++kt) {
    // A tile: BM rows x 64 u16, per wave BM/4 rows, 8 rows per call
#pragma unroll
    for (int j = 0; j < BM / 32; ++j) {
      int row = wid * (BM / 4) + j * 8 + r8;
      gl_lds16(Ab + (long)(xb * BM + row) * 1024 + kt * 64 + c8s * 8,
               (char*)a_lds + wid * (BM * 32) + j * 1024);
    }
    // B tile: 128 rows
#pragma unroll
    for (int j = 0; j < 4; ++j) {
      int row = wid * 32 + j * 8 + r8;
      gl_lds16(Bb + (long)(yb * 128 + row) * 1024 + kt * 64 + c8s * 8,
               (char*)b_lds + wid * 4096 + j * 1024);
    }
    __syncthreads();
#pragma unroll
    for (int kk = 0; kk < 2; ++kk) {
      const int csw = ((kk * 4 + g) ^ (fr & 7)) << 4;
      bf16x8 af[WTM], bq[4];
#pragma unroll
      for (int mi = 0; mi < WTM; ++mi)
        af[mi] = *(const bf16x8*)((const char*)a_lds +
                 (wm * (BM / 2) + mi * 16 + fr) * 128 + csw);
#pragma unroll
      for (int ni = 0; ni < 4; ++ni)
        bq[ni] = *(const bf16x8*)((const char*)b_lds +
                 (wn * 64 + ni * 16 + fr) * 128 + csw);
#pragma unroll
      for (int mi = 0; mi < WTM; ++mi)
#pragma unroll
        for (int ni = 0; ni < 4; ++ni)
          acc[mi][ni] = mfma16(af[mi], bq[ni], acc[mi][ni]);
    }
    __syncthreads();
  }

  const int r4 = ((lane >> 4) & 3) * 4, cc = lane & 15;
  const float* __restrict__ bias = a.bias[z];
  const float post = (MODE == 1 && z == 0) ? a.post : 1.0f;

#pragma unroll
  for (int mi = 0; mi < WTM; ++mi)
#pragma unroll
  for (int ni = 0; ni < 4; ++ni) {
    const int col = yb * 128 + wn * 64 + ni * 16 + cc;
    const float bv = bias[col];
    const int row0 = xb * BM + wm * (BM / 2) + mi * 16 + r4;
    if (MODE == 0) {
      float* O = (float*)a.C[0];
#pragma unroll
      for (int rg = 0; rg < 4; ++rg)
        O[(long)(row0 + rg) * 1024 + col] = acc[mi][ni][rg] + bv;
    } else if (z < 2) {
      u16* O = (u16*)a.C[z];
#pragma unroll
      for (int rg = 0; rg < 4; ++rg) {
        int row = row0 + rg;
        int b = row >> 11, s = row & 2047, h = col >> 6, d = col & 63;
        O[(((long)(b * 16 + h) * 2048 + s) << 6) + d] =
            f2bf((acc[mi][ni][rg] + bv) * post);
      }
    } else {
      u16* O = (u16*)a.C[2];  // V^T: (b*16+h, 64, 2048)
      int b = row0 >> 11, s = row0 & 2047, h = col >> 6, d = col & 63;
      u16x4 o;
#pragma unroll
      for (int rg = 0; rg < 4; ++rg) o[rg] = f2bf(acc[mi][ni][rg] + bv);
      *(u16x4*)&O[((long)(b * 16 + h) * 64 + d) * 2048 + s] = o;
    }
  }
}

// ---- fused attention, swapped-operand layout, exp2 domain ----
// QP pre-scaled by 0.125*log2(e). grid: x=16 q-blocks, z=32 (b*16+h), 4 waves.
// K tile [128][64] and V^T tile [64][128] staged via gload_lds, linear LDS +
// source-swizzled (chunk ^= row&7), reads apply the same XOR.
__global__ __launch_bounds__(256, 3) void k_fused_attn(
    const u16* __restrict__ QP, const u16* __restrict__ KP,
    const u16* __restrict__ VPT, float* __restrict__ attn,
    u16* __restrict__ AO)
{
  __shared__ u16 k_lds[128 * 64];     // 16 KB
  __shared__ u16 vt_lds[64 * 128];    // 16 KB
  __shared__ u16 p_lds[4 * 16 * 128]; // 16 KB (per-wave 4 KB, XOR-swizzled)

  const int t = threadIdx.x, lane = t & 63, w = t >> 6;
  const int fr = lane & 15, g = lane >> 4;
  const int zz = blockIdx.z;
  const int b = zz >> 4, h = zz & 15;
  const int q0 = blockIdx.x * 128;
  const long headQK = (long)zz * (2048 * 64);
  const long headVT = (long)zz * (64 * 2048);
  const int c8s = (lane & 7) ^ ((lane >> 3) & 7);
  const int r8 = lane >> 3;

  bf16x8 aq[2][2];
#pragma unroll
  for (int mi = 0; mi < 2; ++mi)
#pragma unroll
    for (int kk = 0; kk < 2; ++kk)
      aq[mi][kk] = *(const bf16x8*)&QP[headQK +
          (long)(q0 + w * 32 + mi * 16 + fr) * 64 + kk * 32 + g * 8];

  float m[2] = {-1e30f, -1e30f}, l[2] = {0.f, 0.f};

  // pass A: row stats (lane-local, exp2 domain)
  for (int kt = 0; kt < 16; ++kt) {
    __syncthreads();
#pragma unroll
    for (int j = 0; j < 4; ++j) {
      int row = w * 32 + j * 8 + r8;
      gl_lds16(KP + headQK + (long)(kt * 128 + row) * 64 + c8s * 8,
               (char*)k_lds + w * 4096 + j * 1024);
    }
    __syncthreads();

#pragma unroll
    for (int mi = 0; mi < 2; ++mi) {
      f32x4 c[8];
#pragma unroll
      for (int ni = 0; ni < 8; ++ni) {
        c[ni] = (f32x4){};
#pragma unroll
        for (int kk = 0; kk < 2; ++kk) {
          bf16x8 bk = *(const bf16x8*)((const char*)k_lds +
                      (ni * 16 + fr) * 128 + (((kk * 4 + g) ^ (fr & 7)) << 4));
          c[ni] = mfma16(bk, aq[mi][kk], c[ni]);
        }
      }
      float mx01 = -1e30f, mx23 = -1e30f;
#pragma unroll
      for (int ni = 0; ni < 8; ++ni) {
        mx01 = fmaxf(mx01, fmaxf(c[ni][0], c[ni][1]));
        mx23 = fmaxf(mx23, fmaxf(c[ni][2], c[ni][3]));
      }
      float mn = fmaxf(m[mi], fmaxf(mx01, mx23));
      float s = 0.f;
#pragma unroll
      for (int ni = 0; ni < 8; ++ni)
#pragma unroll
        for (int rg = 0; rg < 4; ++rg) s += fexp2(c[ni][rg] - mn);
      l[mi] = l[mi] * fexp2(m[mi] - mn) + s;
      m[mi] = mn;
    }
  }

  float invl[2];
#pragma unroll
  for (int mi = 0; mi < 2; ++mi) {
    float mo = m[mi], lo = l[mi];
#pragma unroll
    for (int off = 16; off <= 32; off <<= 1) {
      float m2 = __shfl_xor(mo, off);
      float l2 = __shfl_xor(lo, off);
      float mn = fmaxf(mo, m2);
      lo = lo * fexp2(mo - mn) + l2 * fexp2(m2 - mn);
      mo = mn;
    }
    m[mi] = mo;
    invl[mi] = 1.0f / lo;
  }

  f32x4 acc[2][4] = {};
  char* pw = (char*)&p_lds[w * 2048];
  const int qrow_base = q0 + w * 32 + fr;

  // pass B: attn write + PV
  for (int kt = 0; kt < 16; ++kt) {
    __syncthreads();
#pragma unroll
    for (int j = 0; j < 4; ++j) {
      int row = w * 32 + j * 8 + r8;
      gl_lds16(KP + headQK + (long)(kt * 128 + row) * 64 + c8s * 8,
               (char*)k_lds + w * 4096 + j * 1024);
    }
#pragma unroll
    for (int j = 0; j < 4; ++j) {
      int row = w * 16 + j * 4 + (lane >> 4);
      int c16s = (lane & 15) ^ (row & 7);
      gl_lds16(VPT + headVT + (long)row * 2048 + kt * 128 + c16s * 8,
               (char*)vt_lds + w * 4096 + j * 1024);
    }
    __syncthreads();

#pragma unroll
    for (int mi = 0; mi < 2; ++mi) {
      const long arow = ((long)zz * 2048 + qrow_base + mi * 16) * 2048 + kt * 128;
#pragma unroll
      for (int ni = 0; ni < 8; ++ni) {
        f32x4 c = (f32x4){};
#pragma unroll
        for (int kk = 0; kk < 2; ++kk) {
          bf16x8 bk = *(const bf16x8*)((const char*)k_lds +
                      (ni * 16 + fr) * 128 + (((kk * 4 + g) ^ (fr & 7)) << 4));
          c = mfma16(bk, aq[mi][kk], c);
        }
        f32x4 p;
#pragma unroll
        for (int rg = 0; rg < 4; ++rg)
          p[rg] = fexp2(c[rg] - m[mi]) * invl[mi];
        *(f32x4*)&attn[arow + ni * 16 + g * 4] = p;
        union { u16x4 us; u64 ull; } pk;
#pragma unroll
        for (int rg = 0; rg < 4; ++rg) pk.us[rg] = f2bf(p[rg]);
        int byte = (fr << 8) + ((ni * 16 + g * 4) << 1);
        byte ^= (fr & 7) << 4;
        *(u64*)(pw + byte) = pk.ull;
      }
#pragma unroll
      for (int kk = 0; kk < 4; ++kk) {
        int byte = (fr << 8) + ((kk * 32 + g * 8) << 1);
        byte ^= (fr & 7) << 4;
        bf16x8 pa = *(const bf16x8*)(pw + byte);
#pragma unroll
        for (int di = 0; di < 4; ++di) {
          bf16x8 bv = *(const bf16x8*)((const char*)vt_lds +
                      (di * 16 + fr) * 256 + (((kk * 4 + g) ^ (fr & 7)) << 4));
          acc[mi][di] = mfma16(pa, bv, acc[mi][di]);
        }
      }
    }
  }

#pragma unroll
  for (int mi = 0; mi < 2; ++mi)
#pragma unroll
  for (int di = 0; di < 4; ++di)
#pragma unroll
  for (int rg = 0; rg < 4; ++rg) {
    int row = q0 + w * 32 + mi * 16 + g * 4 + rg;
    AO[((long)b * 2048 + row) * 1024 + h * 64 + di * 16 + fr] =
        f2bf(acc[mi][di][rg]);
  }
}

extern "C" void kernel_launch(void* const* d_in, const int* in_sizes, int n_in,
                              void* d_out, int out_size, void* d_ws, size_t ws_size,
                              hipStream_t stream) {
  const float* Q  = (const float*)d_in[0];
  const float* Kx = (const float*)d_in[1];
  const float* V  = (const float*)d_in[2];
  const float* Wq = (const float*)d_in[3];
  const float* bq = (const float*)d_in[4];
  const float* Wk = (const float*)d_in[5];
  const float* bk = (const float*)d_in[6];
  const float* Wv = (const float*)d_in[7];
  const float* bv = (const float*)d_in[8];
  const float* Wo = (const float*)d_in[9];
  const float* bo = (const float*)d_in[10];

  float* out  = (float*)d_out;
  float* attn = out + (long)4 * 1024 * 1024;

  // workspace (48 MB): Qb[0-8] (AO overlays after QKV), Kb[8-16],
  // W bf16 [16-24], QP[24-32], KP[32-40], VPT[40-48].
  // Vb (8 MB) lives in the attn region of d_out (written later by attn kernel).
  char* ws = (char*)d_ws;
  const long MB = 1 << 20;
  u16* Qb  = (u16*)(ws + 0 * MB);
  u16* Kb  = (u16*)(ws + 8 * MB);
  u16* Wqb = (u16*)(ws + 16 * MB);
  u16* Wkb = (u16*)(ws + 18 * MB);
  u16* Wvb = (u16*)(ws + 20 * MB);
  u16* Wob = (u16*)(ws + 22 * MB);
  u16* QP  = (u16*)(ws + 24 * MB);
  u16* KP  = (u16*)(ws + 32 * MB);
  u16* VPT = (u16*)(ws + 40 * MB);
  u16* AO  = (u16*)(ws + 0 * MB);   // overlays Qb (dead after QKV GEMM)
  u16* Vb  = (u16*)attn;            // scratch in attn region (overwritten later)

  const int M1 = 1 << 20;
  PrepArgs pa;
  for (int j = 0; j < 4; ++j) { pa.s[j] = Q + (long)j * M1;      pa.d[j] = Qb + (long)j * M1; }
  for (int j = 0; j < 4; ++j) { pa.s[4 + j] = Kx + (long)j * M1; pa.d[4 + j] = Kb + (long)j * M1; }
  for (int j = 0; j < 4; ++j) { pa.s[8 + j] = V + (long)j * M1;  pa.d[8 + j] = Vb + (long)j * M1; }
  pa.s[12] = Wq; pa.d[12] = Wqb;
  pa.s[13] = Wk; pa.d[13] = Wkb;
  pa.s[14] = Wv; pa.d[14] = Wvb;
  pa.s[15] = Wo; pa.d[15] = Wob;
  k_prep<<<8192, 256, 0, stream>>>(pa);

  GArgs gq;
  gq.A[0] = Qb; gq.A[1] = Kb; gq.A[2] = Vb;
  gq.B[0] = Wqb; gq.B[1] = Wkb; gq.B[2] = Wvb;
  gq.bias[0] = bq; gq.bias[1] = bk; gq.bias[2] = bv;
  gq.C[0] = QP; gq.C[1] = KP; gq.C[2] = VPT;
  gq.post = 0.125f * 1.4426950408889634f;  // fold 1/sqrt(dk) and log2(e) into Q
  k_gemm<128, 1><<<768, 256, 0, stream>>>(gq);

  k_fused_attn<<<dim3(16, 1, 32), 256, 0, stream>>>(QP, KP, VPT, attn, AO);

  GArgs go;
  go.A[0] = AO; go.A[1] = AO; go.A[2] = AO;
  go.B[0] = Wob; go.B[1] = Wob; go.B[2] = Wob;
  go.bias[0] = bo; go.bias[1] = bo; go.bias[2] = bo;
  go.C[0] = out; go.C[1] = out; go.C[2] = out;
  go.post = 1.0f;
  k_gemm<64, 0><<<512, 256, 0, stream>>>(go);
}